// Round 10
// baseline (250.666 us; speedup 1.0000x reference)
//
#include <hip/hip_runtime.h>

#define N_EDGES  800000
#define N_NODES  50000
#define IN_DIM   64
#define EDGE_DIM 32
#define HID      96
#define OUT_DIM  64
#define BE       128              // CSR slots per tile
#define PAD      104              // LDS row stride (bf16): 208 B
#define NTILES   (N_EDGES / BE)   // 6250 exactly
#define THREADS  512
#define GRID     512              // 2 blocks/CU, persistent
#define SCAN_B   1024
#define SCAN_NB  ((N_NODES + SCAN_B - 1) / SCAN_B)   // 49

typedef __attribute__((ext_vector_type(8))) short  short8;
typedef __attribute__((ext_vector_type(4))) ushort bf16x4;
typedef __attribute__((ext_vector_type(4))) float  f32x4;

__device__ inline ushort f2bf(float f) {
    union { float f; unsigned u; } v; v.f = f;
    unsigned r = v.u + 0x7FFFu + ((v.u >> 16) & 1u);   // round-to-nearest-even
    return (ushort)(r >> 16);
}
__device__ inline float b2f(ushort u) {
    union { unsigned u; float f; } v; v.u = ((unsigned)u) << 16;
    return v.f;
}

// ---------------------------------------------------------------------------
// CSR-build kernels
// ---------------------------------------------------------------------------
__global__ __launch_bounds__(256) void hist_kernel(const int* __restrict__ ei,
                                                   int* __restrict__ hist) {
    int e = blockIdx.x * 256 + threadIdx.x;
    if (e < N_EDGES) atomicAdd(&hist[ei[N_EDGES + e]], 1);
}

__global__ __launch_bounds__(SCAN_B) void scan1_kernel(const int* __restrict__ hist,
                                                       int* __restrict__ starts,
                                                       int* __restrict__ bsums) {
    __shared__ int buf[2][SCAN_B];
    const int tid = threadIdx.x;
    const int gid = blockIdx.x * SCAN_B + tid;
    int v = (gid < N_NODES) ? hist[gid] : 0;
    int cur = 0;
    buf[0][tid] = v;
    __syncthreads();
    #pragma unroll
    for (int off = 1; off < SCAN_B; off <<= 1) {
        int t = buf[cur][tid] + ((tid >= off) ? buf[cur][tid - off] : 0);
        buf[cur ^ 1][tid] = t;
        __syncthreads();
        cur ^= 1;
    }
    int incl = buf[cur][tid];
    if (gid < N_NODES) starts[gid] = incl;
    if (tid == SCAN_B - 1) bsums[blockIdx.x] = incl;
}

__global__ __launch_bounds__(SCAN_B) void scan3_kernel(const int* __restrict__ hist,
                                                       int* __restrict__ starts,
                                                       int* __restrict__ cursor,
                                                       const int* __restrict__ bsums) {
    __shared__ int s_off;
    if (threadIdx.x < 64) {
        int v = ((int)threadIdx.x < (int)blockIdx.x) ? bsums[threadIdx.x] : 0;
        #pragma unroll
        for (int o = 32; o >= 1; o >>= 1) v += __shfl_xor(v, o, 64);
        if (threadIdx.x == 0) s_off = v;
    }
    __syncthreads();
    const int gid = blockIdx.x * SCAN_B + threadIdx.x;
    if (gid < N_NODES) {
        int e = starts[gid] - hist[gid] + s_off;
        starts[gid] = e;
        cursor[gid] = e;
    }
}

// fill: scatter per-slot arrays so the MLP walks edges in CSR (dst-sorted) order
__global__ __launch_bounds__(256) void fill_kernel(const int* __restrict__ ei,
                                                   int* __restrict__ cursor,
                                                   int* __restrict__ srcs,
                                                   int* __restrict__ eids,
                                                   int* __restrict__ dsts) {
    int e = blockIdx.x * 256 + threadIdx.x;
    if (e < N_EDGES) {
        int c = ei[N_EDGES + e];
        int p = atomicAdd(&cursor[c], 1);
        srcs[p] = ei[e];
        eids[p] = e;
        dsts[p] = c;
    }
}

// ---------------------------------------------------------------------------
// Fallback-path helpers
// ---------------------------------------------------------------------------
__global__ __launch_bounds__(256) void zero_kernel(float* __restrict__ out,
                                                   float* __restrict__ cnt) {
    int i = blockIdx.x * 256 + threadIdx.x;
    if (i < N_NODES * OUT_DIM) out[i] = 0.0f;
    if (i < N_NODES) cnt[i] = 0.0f;
}

__global__ __launch_bounds__(256) void div_kernel(float* __restrict__ out,
                                                  const float* __restrict__ cnt) {
    int i = blockIdx.x * 256 + threadIdx.x;
    if (i < N_NODES * OUT_DIM) {
        float c = cnt[i / OUT_DIM];
        out[i] = out[i] / fmaxf(c, 1.0f);
    }
}

// div by int hist (main path)
__global__ __launch_bounds__(256) void div_int_kernel(float* __restrict__ out,
                                                      const int* __restrict__ hist) {
    int i = blockIdx.x * 256 + threadIdx.x;
    if (i < N_NODES * OUT_DIM) {
        float c = (float)hist[i >> 6];
        out[i] = out[i] / fmaxf(c, 1.0f);
    }
}

// ---------------------------------------------------------------------------
// MAIN: fused gather -> bf16 MFMA MLP -> in-wave segment reduce -> atomicAdd.
// Edges are processed in CSR (dst-sorted) order via srcs/eids/dsts. Each wave
// owns 16 CSR slots per tile; after GEMM2 it segment-sums its 16 rows (sorted
// dst keys) in LDS and flushes one coalesced 256-B atomicAdd per segment.
// Gather uses the proven 4-lane x float4 full-line pattern (round-6/8:
// FETCH ~138 MB; round-9's per-lg 16B scatter cost +115 MB - do not revisit).
// ---------------------------------------------------------------------------
__global__ __launch_bounds__(THREADS, 4) void edge_mlp_csr_kernel(
    const float* __restrict__ x,
    const float* __restrict__ ea,
    const int*   __restrict__ srcs,   // [E] src node per CSR slot
    const int*   __restrict__ eids,   // [E] edge id per CSR slot
    const int*   __restrict__ dsts,   // [E] dst node per CSR slot (sorted)
    const float* __restrict__ W1,     // [HID, HID] row-major (k, n)
    const float* __restrict__ b1,
    const float* __restrict__ W2,     // [HID, OUT] row-major (k, n)
    const float* __restrict__ b2,
    float*       __restrict__ out)    // [N, OUT] accumulator (pre-zeroed)
{
    __shared__ ushort sA[BE][PAD];        // input tile -> H -> O (per-wave rows)
    __shared__ ushort sW1T[HID][PAD];     // W1 transposed: [n][k]
    __shared__ ushort sW2T[OUT_DIM][PAD]; // W2 transposed: [n][k] (staging)

    const int tid  = threadIdx.x;
    const int wave = tid >> 6;
    const int lane = tid & 63;
    const int lr   = lane & 15;
    const int lg   = lane >> 4;
    const int el_base = wave * 16;
    const int el   = el_base + (lane >> 2);   // gather row owned by this lane
    const int part = lane & 3;

    // ---- stage weights (bf16, transposed), float4-vectorized ----
    #pragma unroll 2
    for (int i = tid; i < HID * HID / 4; i += THREADS) {
        float4 v = reinterpret_cast<const float4*>(W1)[i];
        int k = (i * 4) / HID, n = (i * 4) % HID;
        sW1T[n + 0][k] = f2bf(v.x); sW1T[n + 1][k] = f2bf(v.y);
        sW1T[n + 2][k] = f2bf(v.z); sW1T[n + 3][k] = f2bf(v.w);
    }
    #pragma unroll 2
    for (int i = tid; i < HID * OUT_DIM / 4; i += THREADS) {
        float4 v = reinterpret_cast<const float4*>(W2)[i];
        int k = (i * 4) / OUT_DIM, n = (i * 4) % OUT_DIM;
        sW2T[n + 0][k] = f2bf(v.x); sW2T[n + 1][k] = f2bf(v.y);
        sW2T[n + 2][k] = f2bf(v.z); sW2T[n + 3][k] = f2bf(v.w);
    }
    float rb1[6], rb2[4];
    #pragma unroll
    for (int nt = 0; nt < 6; ++nt) rb1[nt] = b1[nt * 16 + lr];
    #pragma unroll
    for (int nt = 0; nt < 4; ++nt) rb2[nt] = b2[nt * 16 + lr];
    __syncthreads();

    // ---- hoist W2 fragments to registers (one-time; 12 x short8) ----
    short8 bw2[4][3];
    #pragma unroll
    for (int nt = 0; nt < 4; ++nt)
        #pragma unroll
        for (int ks = 0; ks < 3; ++ks)
            bw2[nt][ks] = *(const short8*)&sW2T[nt * 16 + lr][ks * 32 + lg * 8];

    for (int tl = blockIdx.x; tl < NTILES; tl += GRID) {
        const int e0 = tl * BE;

        // ---- gather: 4 lanes per slot, 6 float4 each (full-line pattern) ----
        {
            const int slot = e0 + el;
            const int src  = srcs[slot];
            const int eid  = eids[slot];
            const float4* xp = reinterpret_cast<const float4*>(x) + (size_t)src * 16;
            const float4* ep = reinterpret_cast<const float4*>(ea) + (size_t)eid * 8;
            #pragma unroll
            for (int i = 0; i < 6; ++i) {
                const int f = part + 4 * i;            // 0..23; i<4 -> x, else ea
                float4 v = (i < 4) ? xp[f] : ep[f - 16];
                bf16x4 w = { f2bf(v.x), f2bf(v.y), f2bf(v.z), f2bf(v.w) };
                *(bf16x4*)&sA[el][f * 4] = w;
            }
        }
        // ---- preload this wave's 16 sorted dst keys (uniform loads) ----
        int dreg[17];
        #pragma unroll
        for (int r = 0; r < 16; ++r) dreg[r] = dsts[e0 + el_base + r];
        dreg[16] = -1;

        asm volatile("s_waitcnt lgkmcnt(0)" ::: "memory");
        __builtin_amdgcn_sched_barrier(0);

        // ---- GEMM1: H = relu(A @ W1 + b1) ----
        short8 af[3];
        #pragma unroll
        for (int ks = 0; ks < 3; ++ks)
            af[ks] = *(const short8*)&sA[el_base + lr][ks * 32 + lg * 8];

        f32x4 acc1[6];
        #pragma unroll
        for (int nt = 0; nt < 6; ++nt) {
            float bv = rb1[nt];
            acc1[nt] = f32x4{ bv, bv, bv, bv };
        }
        #pragma unroll
        for (int nt = 0; nt < 6; ++nt) {
            short8 bf[3];
            #pragma unroll
            for (int ks = 0; ks < 3; ++ks)
                bf[ks] = *(const short8*)&sW1T[nt * 16 + lr][ks * 32 + lg * 8];
            #pragma unroll
            for (int ks = 0; ks < 3; ++ks)
                acc1[nt] = __builtin_amdgcn_mfma_f32_16x16x32_bf16(
                    af[ks], bf[ks], acc1[nt], 0, 0, 0);
        }

        // ---- ReLU + H bounce via sA (D layout: col=lr, row=lg*4+j) ----
        #pragma unroll
        for (int nt = 0; nt < 6; ++nt)
            #pragma unroll
            for (int j = 0; j < 4; ++j)
                sA[el_base + lg * 4 + j][nt * 16 + lr] =
                    f2bf(fmaxf(acc1[nt][j], 0.0f));
        asm volatile("s_waitcnt lgkmcnt(0)" ::: "memory");
        __builtin_amdgcn_sched_barrier(0);

        // ---- GEMM2: O = H @ W2 + b2 (W2 from regs) ----
        short8 a2[3];
        #pragma unroll
        for (int ks = 0; ks < 3; ++ks)
            a2[ks] = *(const short8*)&sA[el_base + lr][ks * 32 + lg * 8];

        f32x4 acc2[4];
        #pragma unroll
        for (int nt = 0; nt < 4; ++nt) {
            float bv = rb2[nt];
            acc2[nt] = f32x4{ bv, bv, bv, bv };
        }
        #pragma unroll
        for (int nt = 0; nt < 4; ++nt)
            #pragma unroll
            for (int ks = 0; ks < 3; ++ks)
                acc2[nt] = __builtin_amdgcn_mfma_f32_16x16x32_bf16(
                    a2[ks], bw2[nt][ks], acc2[nt], 0, 0, 0);

        // ---- O bounce via sA (bf16) ----
        #pragma unroll
        for (int nt = 0; nt < 4; ++nt)
            #pragma unroll
            for (int j = 0; j < 4; ++j)
                sA[el_base + lg * 4 + j][nt * 16 + lr] = f2bf(acc2[nt][j]);
        asm volatile("s_waitcnt lgkmcnt(0)" ::: "memory");
        __builtin_amdgcn_sched_barrier(0);

        // ---- segment reduce: lane owns column `lane`; dsts sorted -> flush
        //      one coalesced 256-B atomicAdd row per segment ----
        float s = 0.0f;
        #pragma unroll
        for (int r = 0; r < 16; ++r) {
            s += b2f(sA[el_base + r][lane]);
            if (r == 15 || dreg[r + 1] != dreg[r]) {
                atomicAdd(out + (size_t)dreg[r] * OUT_DIM + lane, s);
                s = 0.0f;
            }
        }
        // next tile's gather writes these same per-wave rows; same-wave DS
        // ops are in-order, so reads above retire before those writes land.
    }
}

// ---------------------------------------------------------------------------
// Fallback (ws too small): round-8 atomic-scatter kernel, edge order.
// ---------------------------------------------------------------------------
__global__ __launch_bounds__(THREADS, 4) void edge_mlp_atomic_kernel(
    const float* __restrict__ x,
    const int*   __restrict__ ei,
    const float* __restrict__ ea,
    const float* __restrict__ W1,
    const float* __restrict__ b1,
    const float* __restrict__ W2,
    const float* __restrict__ b2,
    float*       __restrict__ out,
    float*       __restrict__ cnt)
{
    __shared__ ushort sA[BE][PAD];
    __shared__ ushort sW1T[HID][PAD];
    __shared__ ushort sW2T[OUT_DIM][PAD];

    const int tid  = threadIdx.x;
    const int wave = tid >> 6;
    const int lane = tid & 63;
    const int lr   = lane & 15;
    const int lg   = lane >> 4;
    const int el_base = wave * 16;
    const int el   = el_base + (lane >> 2);
    const int part = lane & 3;

    #pragma unroll 2
    for (int i = tid; i < HID * HID / 4; i += THREADS) {
        float4 v = reinterpret_cast<const float4*>(W1)[i];
        int k = (i * 4) / HID, n = (i * 4) % HID;
        sW1T[n + 0][k] = f2bf(v.x); sW1T[n + 1][k] = f2bf(v.y);
        sW1T[n + 2][k] = f2bf(v.z); sW1T[n + 3][k] = f2bf(v.w);
    }
    #pragma unroll 2
    for (int i = tid; i < HID * OUT_DIM / 4; i += THREADS) {
        float4 v = reinterpret_cast<const float4*>(W2)[i];
        int k = (i * 4) / OUT_DIM, n = (i * 4) % OUT_DIM;
        sW2T[n + 0][k] = f2bf(v.x); sW2T[n + 1][k] = f2bf(v.y);
        sW2T[n + 2][k] = f2bf(v.z); sW2T[n + 3][k] = f2bf(v.w);
    }
    float rb1[6], rb2[4];
    #pragma unroll
    for (int nt = 0; nt < 6; ++nt) rb1[nt] = b1[nt * 16 + lr];
    #pragma unroll
    for (int nt = 0; nt < 4; ++nt) rb2[nt] = b2[nt * 16 + lr];
    __syncthreads();

    short8 bw2[4][3];
    #pragma unroll
    for (int nt = 0; nt < 4; ++nt)
        #pragma unroll
        for (int ks = 0; ks < 3; ++ks)
            bw2[nt][ks] = *(const short8*)&sW2T[nt * 16 + lr][ks * 32 + lg * 8];

    for (int tl = blockIdx.x; tl < NTILES; tl += GRID) {
        const int e0 = tl * BE;
        {
            const int e   = e0 + el;
            const int src = ei[e];
            const float4* xp = reinterpret_cast<const float4*>(x) + (size_t)src * 16;
            const float4* ep = reinterpret_cast<const float4*>(ea) + (size_t)e * 8;
            #pragma unroll
            for (int i = 0; i < 6; ++i) {
                const int f = part + 4 * i;
                float4 v = (i < 4) ? xp[f] : ep[f - 16];
                bf16x4 w = { f2bf(v.x), f2bf(v.y), f2bf(v.z), f2bf(v.w) };
                *(bf16x4*)&sA[el][f * 4] = w;
            }
            if (part == 0) atomicAdd(cnt + ei[N_EDGES + e], 1.0f);
        }
        asm volatile("s_waitcnt lgkmcnt(0)" ::: "memory");
        __builtin_amdgcn_sched_barrier(0);

        short8 af[3];
        #pragma unroll
        for (int ks = 0; ks < 3; ++ks)
            af[ks] = *(const short8*)&sA[el_base + lr][ks * 32 + lg * 8];
        f32x4 acc1[6];
        #pragma unroll
        for (int nt = 0; nt < 6; ++nt) {
            float bv = rb1[nt];
            acc1[nt] = f32x4{ bv, bv, bv, bv };
        }
        #pragma unroll
        for (int nt = 0; nt < 6; ++nt) {
            short8 bf[3];
            #pragma unroll
            for (int ks = 0; ks < 3; ++ks)
                bf[ks] = *(const short8*)&sW1T[nt * 16 + lr][ks * 32 + lg * 8];
            #pragma unroll
            for (int ks = 0; ks < 3; ++ks)
                acc1[nt] = __builtin_amdgcn_mfma_f32_16x16x32_bf16(
                    af[ks], bf[ks], acc1[nt], 0, 0, 0);
        }
        #pragma unroll
        for (int nt = 0; nt < 6; ++nt)
            #pragma unroll
            for (int j = 0; j < 4; ++j)
                sA[el_base + lg * 4 + j][nt * 16 + lr] =
                    f2bf(fmaxf(acc1[nt][j], 0.0f));
        asm volatile("s_waitcnt lgkmcnt(0)" ::: "memory");
        __builtin_amdgcn_sched_barrier(0);

        short8 a2[3];
        #pragma unroll
        for (int ks = 0; ks < 3; ++ks)
            a2[ks] = *(const short8*)&sA[el_base + lr][ks * 32 + lg * 8];
        f32x4 acc2[4];
        #pragma unroll
        for (int nt = 0; nt < 4; ++nt) {
            float bv = rb2[nt];
            acc2[nt] = f32x4{ bv, bv, bv, bv };
        }
        #pragma unroll
        for (int nt = 0; nt < 4; ++nt)
            #pragma unroll
            for (int ks = 0; ks < 3; ++ks)
                acc2[nt] = __builtin_amdgcn_mfma_f32_16x16x32_bf16(
                    a2[ks], bw2[nt][ks], acc2[nt], 0, 0, 0);

        int nd[4];
        #pragma unroll
        for (int j = 0; j < 4; ++j)
            nd[j] = ei[N_EDGES + e0 + el_base + lg * 4 + j];
        #pragma unroll
        for (int nt = 0; nt < 4; ++nt)
            #pragma unroll
            for (int j = 0; j < 4; ++j)
                atomicAdd(out + (size_t)nd[j] * OUT_DIM + nt * 16 + lr,
                          acc2[nt][j]);
    }
}

extern "C" void kernel_launch(void* const* d_in, const int* in_sizes, int n_in,
                              void* d_out, int out_size, void* d_ws, size_t ws_size,
                              hipStream_t stream) {
    const float* x  = (const float*)d_in[0];
    const int*   ei = (const int*)d_in[1];
    const float* ea = (const float*)d_in[2];
    const float* W1 = (const float*)d_in[3];
    const float* b1 = (const float*)d_in[4];
    const float* W2 = (const float*)d_in[5];
    const float* b2 = (const float*)d_in[6];
    float* out = (float*)d_out;

    // ws layout: srcs[E] | eids[E] | dsts[E] | hist[N] | starts[N] | cursor[N] | bsums[64]
    char* ws = (char*)d_ws;
    const size_t srcsOff = 0;
    const size_t eidsOff = srcsOff + (size_t)N_EDGES * 4;
    const size_t dstsOff = eidsOff + (size_t)N_EDGES * 4;
    const size_t histOff = dstsOff + (size_t)N_EDGES * 4;
    const size_t strOff  = histOff + (size_t)N_NODES * 4;
    const size_t curOff  = strOff + (size_t)N_NODES * 4;
    const size_t bsumOff = curOff + (size_t)N_NODES * 4;
    const size_t need    = bsumOff + 64 * 4;

    if (ws_size >= need) {
        int* srcs   = (int*)(ws + srcsOff);
        int* eids   = (int*)(ws + eidsOff);
        int* dsts   = (int*)(ws + dstsOff);
        int* hist   = (int*)(ws + histOff);
        int* starts = (int*)(ws + strOff);
        int* cursor = (int*)(ws + curOff);
        int* bsums  = (int*)(ws + bsumOff);

        hipMemsetAsync(hist, 0, (size_t)N_NODES * 4, stream);
        hipMemsetAsync(out, 0, (size_t)N_NODES * OUT_DIM * 4, stream);
        hist_kernel<<<N_EDGES / 256, 256, 0, stream>>>(ei, hist);
        scan1_kernel<<<SCAN_NB, SCAN_B, 0, stream>>>(hist, starts, bsums);
        scan3_kernel<<<SCAN_NB, SCAN_B, 0, stream>>>(hist, starts, cursor, bsums);
        fill_kernel<<<N_EDGES / 256, 256, 0, stream>>>(ei, cursor, srcs, eids, dsts);
        edge_mlp_csr_kernel<<<GRID, THREADS, 0, stream>>>(
            x, ea, srcs, eids, dsts, W1, b1, W2, b2, out);
        div_int_kernel<<<(N_NODES * OUT_DIM + 255) / 256, 256, 0, stream>>>(out, hist);
    } else {
        // fallback: atomic scatter path
        float* cnt = (float*)d_ws;  // N_NODES floats
        zero_kernel<<<(N_NODES * OUT_DIM + 255) / 256, 256, 0, stream>>>(out, cnt);
        edge_mlp_atomic_kernel<<<GRID, THREADS, 0, stream>>>(
            x, ei, ea, W1, b1, W2, b2, out, cnt);
        div_kernel<<<(N_NODES * OUT_DIM + 255) / 256, 256, 0, stream>>>(out, cnt);
    }
}

// Round 11
// 223.549 us; speedup vs baseline: 1.1213x; 1.1213x over previous
//
#include <hip/hip_runtime.h>

#define N_EDGES  800000
#define N_NODES  50000
#define IN_DIM   64
#define EDGE_DIM 32
#define HID      96
#define OUT_DIM  64
#define BE       128              // CSR slots per tile
#define PAD      104              // LDS row stride (bf16): 208 B
#define NTILES   (N_EDGES / BE)   // 6250 exactly
#define THREADS  512
#define GRID     512              // 2 blocks/CU, persistent
#define SCAN_B   1024
#define SCAN_NB  ((N_NODES + SCAN_B - 1) / SCAN_B)   // 49

typedef __attribute__((ext_vector_type(8))) short  short8;
typedef __attribute__((ext_vector_type(4))) ushort bf16x4;
typedef __attribute__((ext_vector_type(4))) float  f32x4;

__device__ inline ushort f2bf(float f) {
    union { float f; unsigned u; } v; v.f = f;
    unsigned r = v.u + 0x7FFFu + ((v.u >> 16) & 1u);   // round-to-nearest-even
    return (ushort)(r >> 16);
}
__device__ inline float b2f(ushort u) {
    union { unsigned u; float f; } v; v.u = ((unsigned)u) << 16;
    return v.f;
}

// ---------------------------------------------------------------------------
// CSR-build kernels
// ---------------------------------------------------------------------------
__global__ __launch_bounds__(256) void hist_kernel(const int* __restrict__ ei,
                                                   int* __restrict__ hist) {
    int e = blockIdx.x * 256 + threadIdx.x;
    if (e < N_EDGES) atomicAdd(&hist[ei[N_EDGES + e]], 1);
}

__global__ __launch_bounds__(SCAN_B) void scan1_kernel(const int* __restrict__ hist,
                                                       int* __restrict__ starts,
                                                       int* __restrict__ bsums) {
    __shared__ int buf[2][SCAN_B];
    const int tid = threadIdx.x;
    const int gid = blockIdx.x * SCAN_B + tid;
    int v = (gid < N_NODES) ? hist[gid] : 0;
    int cur = 0;
    buf[0][tid] = v;
    __syncthreads();
    #pragma unroll
    for (int off = 1; off < SCAN_B; off <<= 1) {
        int t = buf[cur][tid] + ((tid >= off) ? buf[cur][tid - off] : 0);
        buf[cur ^ 1][tid] = t;
        __syncthreads();
        cur ^= 1;
    }
    int incl = buf[cur][tid];
    if (gid < N_NODES) starts[gid] = incl;
    if (tid == SCAN_B - 1) bsums[blockIdx.x] = incl;
}

__global__ __launch_bounds__(SCAN_B) void scan3_kernel(const int* __restrict__ hist,
                                                       int* __restrict__ starts,
                                                       int* __restrict__ cursor,
                                                       const int* __restrict__ bsums) {
    __shared__ int s_off;
    if (threadIdx.x < 64) {
        int v = ((int)threadIdx.x < (int)blockIdx.x) ? bsums[threadIdx.x] : 0;
        #pragma unroll
        for (int o = 32; o >= 1; o >>= 1) v += __shfl_xor(v, o, 64);
        if (threadIdx.x == 0) s_off = v;
    }
    __syncthreads();
    const int gid = blockIdx.x * SCAN_B + threadIdx.x;
    if (gid < N_NODES) {
        int e = starts[gid] - hist[gid] + s_off;
        starts[gid] = e;
        cursor[gid] = e;
    }
}

// x -> bf16 (6.4 MB; halves gather bytes and L2 footprint in the MLP)
__global__ __launch_bounds__(256) void xbf_kernel(const float* __restrict__ x,
                                                  ushort* __restrict__ xb) {
    int i = blockIdx.x * 256 + threadIdx.x;   // over float4s: N*16
    if (i < N_NODES * 16) {
        float4 v = reinterpret_cast<const float4*>(x)[i];
        bf16x4 w = { f2bf(v.x), f2bf(v.y), f2bf(v.z), f2bf(v.w) };
        *(bf16x4*)&xb[i * 4] = w;
    }
}

// fill_permute: 4 lanes per edge. Sequential ea read (the law from r10:
// random READS amplify ~2.8x; random WRITES are free, r8) -> bf16 row write
// at CSR slot p. Also writes srcs[p], dsts[p].
__global__ __launch_bounds__(256) void fill_permute_kernel(
    const int*   __restrict__ ei,
    const float* __restrict__ ea,
    int*         __restrict__ cursor,
    int*         __restrict__ srcs,
    int*         __restrict__ dsts,
    ushort*      __restrict__ eap)    // [E, 32] bf16, CSR-ordered
{
    const int lane4 = threadIdx.x & 3;
    const int e = blockIdx.x * 64 + (threadIdx.x >> 2);   // grid exact: E/64
    int p = 0;
    if (lane4 == 0) {
        int c = ei[N_EDGES + e];
        p = atomicAdd(&cursor[c], 1);
        srcs[p] = ei[e];
        dsts[p] = c;
    }
    p = __shfl(p, (threadIdx.x & 63) & ~3, 64);
    const float4* ep = reinterpret_cast<const float4*>(ea) + (size_t)e * 8 + lane4 * 2;
    float4 a = ep[0], b = ep[1];
    short8 v = { (short)f2bf(a.x), (short)f2bf(a.y), (short)f2bf(a.z), (short)f2bf(a.w),
                 (short)f2bf(b.x), (short)f2bf(b.y), (short)f2bf(b.z), (short)f2bf(b.w) };
    *(short8*)&eap[(size_t)p * 32 + lane4 * 8] = v;
}

// ---------------------------------------------------------------------------
// Fallback-path helpers
// ---------------------------------------------------------------------------
__global__ __launch_bounds__(256) void zero_kernel(float* __restrict__ out,
                                                   float* __restrict__ cnt) {
    int i = blockIdx.x * 256 + threadIdx.x;
    if (i < N_NODES * OUT_DIM) out[i] = 0.0f;
    if (i < N_NODES) cnt[i] = 0.0f;
}

__global__ __launch_bounds__(256) void div_kernel(float* __restrict__ out,
                                                  const float* __restrict__ cnt) {
    int i = blockIdx.x * 256 + threadIdx.x;
    if (i < N_NODES * OUT_DIM) {
        float c = cnt[i / OUT_DIM];
        out[i] = out[i] / fmaxf(c, 1.0f);
    }
}

__global__ __launch_bounds__(256) void div_int_kernel(float* __restrict__ out,
                                                      const int* __restrict__ hist) {
    int i = blockIdx.x * 256 + threadIdx.x;
    if (i < N_NODES * OUT_DIM) {
        float c = (float)hist[i >> 6];
        out[i] = out[i] / fmaxf(c, 1.0f);
    }
}

// ---------------------------------------------------------------------------
// MAIN: CSR-ordered fused MLP. All big reads sequential (eap) or cache-hot
// (xbf, 6.4 MB). Segment reduce + coalesced atomics (proven r10).
// ---------------------------------------------------------------------------
__global__ __launch_bounds__(THREADS, 4) void edge_mlp_csr_kernel(
    const ushort* __restrict__ xbf,    // [N, 64] bf16
    const ushort* __restrict__ eap,    // [E, 32] bf16, CSR-ordered
    const int*    __restrict__ srcs,   // [E] src node per CSR slot
    const int*    __restrict__ dsts,   // [E] dst node per CSR slot (sorted)
    const float*  __restrict__ W1,
    const float*  __restrict__ b1,
    const float*  __restrict__ W2,
    const float*  __restrict__ b2,
    float*        __restrict__ out)    // [N, OUT] accumulator (pre-zeroed)
{
    __shared__ ushort sA[BE][PAD];
    __shared__ ushort sW1T[HID][PAD];
    __shared__ ushort sW2T[OUT_DIM][PAD];

    const int tid  = threadIdx.x;
    const int wave = tid >> 6;
    const int lane = tid & 63;
    const int lr   = lane & 15;
    const int lg   = lane >> 4;
    const int el_base = wave * 16;
    const int el   = el_base + (lane >> 2);
    const int part = lane & 3;

    #pragma unroll 2
    for (int i = tid; i < HID * HID / 4; i += THREADS) {
        float4 v = reinterpret_cast<const float4*>(W1)[i];
        int k = (i * 4) / HID, n = (i * 4) % HID;
        sW1T[n + 0][k] = f2bf(v.x); sW1T[n + 1][k] = f2bf(v.y);
        sW1T[n + 2][k] = f2bf(v.z); sW1T[n + 3][k] = f2bf(v.w);
    }
    #pragma unroll 2
    for (int i = tid; i < HID * OUT_DIM / 4; i += THREADS) {
        float4 v = reinterpret_cast<const float4*>(W2)[i];
        int k = (i * 4) / OUT_DIM, n = (i * 4) % OUT_DIM;
        sW2T[n + 0][k] = f2bf(v.x); sW2T[n + 1][k] = f2bf(v.y);
        sW2T[n + 2][k] = f2bf(v.z); sW2T[n + 3][k] = f2bf(v.w);
    }
    float rb1[6], rb2[4];
    #pragma unroll
    for (int nt = 0; nt < 6; ++nt) rb1[nt] = b1[nt * 16 + lr];
    #pragma unroll
    for (int nt = 0; nt < 4; ++nt) rb2[nt] = b2[nt * 16 + lr];
    __syncthreads();

    short8 bw2[4][3];
    #pragma unroll
    for (int nt = 0; nt < 4; ++nt)
        #pragma unroll
        for (int ks = 0; ks < 3; ++ks)
            bw2[nt][ks] = *(const short8*)&sW2T[nt * 16 + lr][ks * 32 + lg * 8];

    for (int tl = blockIdx.x; tl < NTILES; tl += GRID) {
        const int e0 = tl * BE;

        // ---- gather: x row (bf16, cached) + eap row (bf16, SEQUENTIAL) ----
        {
            const int slot = e0 + el;
            const int src  = srcs[slot];
            const short8* xb8 = reinterpret_cast<const short8*>(xbf + (size_t)src * 64);
            short8 v0 = xb8[part * 2], v1 = xb8[part * 2 + 1];
            *(short8*)&sA[el][part * 16]     = v0;
            *(short8*)&sA[el][part * 16 + 8] = v1;
            short8 v2 = *(const short8*)(eap + (size_t)slot * 32 + part * 8);
            *(short8*)&sA[el][64 + part * 8] = v2;
        }
        // ---- preload this wave's 16 sorted dst keys ----
        int dreg[17];
        #pragma unroll
        for (int r = 0; r < 16; ++r) dreg[r] = dsts[e0 + el_base + r];
        dreg[16] = -1;

        asm volatile("s_waitcnt lgkmcnt(0)" ::: "memory");
        __builtin_amdgcn_sched_barrier(0);

        // ---- GEMM1: H = relu(A @ W1 + b1) ----
        short8 af[3];
        #pragma unroll
        for (int ks = 0; ks < 3; ++ks)
            af[ks] = *(const short8*)&sA[el_base + lr][ks * 32 + lg * 8];

        f32x4 acc1[6];
        #pragma unroll
        for (int nt = 0; nt < 6; ++nt) {
            float bv = rb1[nt];
            acc1[nt] = f32x4{ bv, bv, bv, bv };
        }
        #pragma unroll
        for (int nt = 0; nt < 6; ++nt) {
            short8 bf[3];
            #pragma unroll
            for (int ks = 0; ks < 3; ++ks)
                bf[ks] = *(const short8*)&sW1T[nt * 16 + lr][ks * 32 + lg * 8];
            #pragma unroll
            for (int ks = 0; ks < 3; ++ks)
                acc1[nt] = __builtin_amdgcn_mfma_f32_16x16x32_bf16(
                    af[ks], bf[ks], acc1[nt], 0, 0, 0);
        }

        // ---- ReLU + H bounce via sA ----
        #pragma unroll
        for (int nt = 0; nt < 6; ++nt)
            #pragma unroll
            for (int j = 0; j < 4; ++j)
                sA[el_base + lg * 4 + j][nt * 16 + lr] =
                    f2bf(fmaxf(acc1[nt][j], 0.0f));
        asm volatile("s_waitcnt lgkmcnt(0)" ::: "memory");
        __builtin_amdgcn_sched_barrier(0);

        // ---- GEMM2: O = H @ W2 + b2 (W2 from regs) ----
        short8 a2[3];
        #pragma unroll
        for (int ks = 0; ks < 3; ++ks)
            a2[ks] = *(const short8*)&sA[el_base + lr][ks * 32 + lg * 8];

        f32x4 acc2[4];
        #pragma unroll
        for (int nt = 0; nt < 4; ++nt) {
            float bv = rb2[nt];
            acc2[nt] = f32x4{ bv, bv, bv, bv };
        }
        #pragma unroll
        for (int nt = 0; nt < 4; ++nt)
            #pragma unroll
            for (int ks = 0; ks < 3; ++ks)
                acc2[nt] = __builtin_amdgcn_mfma_f32_16x16x32_bf16(
                    a2[ks], bw2[nt][ks], acc2[nt], 0, 0, 0);

        // ---- O bounce via sA (bf16) ----
        #pragma unroll
        for (int nt = 0; nt < 4; ++nt)
            #pragma unroll
            for (int j = 0; j < 4; ++j)
                sA[el_base + lg * 4 + j][nt * 16 + lr] = f2bf(acc2[nt][j]);
        asm volatile("s_waitcnt lgkmcnt(0)" ::: "memory");
        __builtin_amdgcn_sched_barrier(0);

        // ---- segment reduce (sorted dsts) -> coalesced atomicAdd per segment ----
        float s = 0.0f;
        #pragma unroll
        for (int r = 0; r < 16; ++r) {
            s += b2f(sA[el_base + r][lane]);
            if (r == 15 || dreg[r + 1] != dreg[r]) {
                atomicAdd(out + (size_t)dreg[r] * OUT_DIM + lane, s);
                s = 0.0f;
            }
        }
    }
}

// ---------------------------------------------------------------------------
// Fallback (ws too small): round-8 atomic-scatter kernel, edge order.
// ---------------------------------------------------------------------------
__global__ __launch_bounds__(THREADS, 4) void edge_mlp_atomic_kernel(
    const float* __restrict__ x,
    const int*   __restrict__ ei,
    const float* __restrict__ ea,
    const float* __restrict__ W1,
    const float* __restrict__ b1,
    const float* __restrict__ W2,
    const float* __restrict__ b2,
    float*       __restrict__ out,
    float*       __restrict__ cnt)
{
    __shared__ ushort sA[BE][PAD];
    __shared__ ushort sW1T[HID][PAD];
    __shared__ ushort sW2T[OUT_DIM][PAD];

    const int tid  = threadIdx.x;
    const int wave = tid >> 6;
    const int lane = tid & 63;
    const int lr   = lane & 15;
    const int lg   = lane >> 4;
    const int el_base = wave * 16;
    const int el   = el_base + (lane >> 2);
    const int part = lane & 3;

    #pragma unroll 2
    for (int i = tid; i < HID * HID / 4; i += THREADS) {
        float4 v = reinterpret_cast<const float4*>(W1)[i];
        int k = (i * 4) / HID, n = (i * 4) % HID;
        sW1T[n + 0][k] = f2bf(v.x); sW1T[n + 1][k] = f2bf(v.y);
        sW1T[n + 2][k] = f2bf(v.z); sW1T[n + 3][k] = f2bf(v.w);
    }
    #pragma unroll 2
    for (int i = tid; i < HID * OUT_DIM / 4; i += THREADS) {
        float4 v = reinterpret_cast<const float4*>(W2)[i];
        int k = (i * 4) / OUT_DIM, n = (i * 4) % OUT_DIM;
        sW2T[n + 0][k] = f2bf(v.x); sW2T[n + 1][k] = f2bf(v.y);
        sW2T[n + 2][k] = f2bf(v.z); sW2T[n + 3][k] = f2bf(v.w);
    }
    float rb1[6], rb2[4];
    #pragma unroll
    for (int nt = 0; nt < 6; ++nt) rb1[nt] = b1[nt * 16 + lr];
    #pragma unroll
    for (int nt = 0; nt < 4; ++nt) rb2[nt] = b2[nt * 16 + lr];
    __syncthreads();

    short8 bw2[4][3];
    #pragma unroll
    for (int nt = 0; nt < 4; ++nt)
        #pragma unroll
        for (int ks = 0; ks < 3; ++ks)
            bw2[nt][ks] = *(const short8*)&sW2T[nt * 16 + lr][ks * 32 + lg * 8];

    for (int tl = blockIdx.x; tl < NTILES; tl += GRID) {
        const int e0 = tl * BE;
        {
            const int e   = e0 + el;
            const int src = ei[e];
            const float4* xp = reinterpret_cast<const float4*>(x) + (size_t)src * 16;
            const float4* ep = reinterpret_cast<const float4*>(ea) + (size_t)e * 8;
            #pragma unroll
            for (int i = 0; i < 6; ++i) {
                const int f = part + 4 * i;
                float4 v = (i < 4) ? xp[f] : ep[f - 16];
                bf16x4 w = { f2bf(v.x), f2bf(v.y), f2bf(v.z), f2bf(v.w) };
                *(bf16x4*)&sA[el][f * 4] = w;
            }
            if (part == 0) atomicAdd(cnt + ei[N_EDGES + e], 1.0f);
        }
        asm volatile("s_waitcnt lgkmcnt(0)" ::: "memory");
        __builtin_amdgcn_sched_barrier(0);

        short8 af[3];
        #pragma unroll
        for (int ks = 0; ks < 3; ++ks)
            af[ks] = *(const short8*)&sA[el_base + lr][ks * 32 + lg * 8];
        f32x4 acc1[6];
        #pragma unroll
        for (int nt = 0; nt < 6; ++nt) {
            float bv = rb1[nt];
            acc1[nt] = f32x4{ bv, bv, bv, bv };
        }
        #pragma unroll
        for (int nt = 0; nt < 6; ++nt) {
            short8 bf[3];
            #pragma unroll
            for (int ks = 0; ks < 3; ++ks)
                bf[ks] = *(const short8*)&sW1T[nt * 16 + lr][ks * 32 + lg * 8];
            #pragma unroll
            for (int ks = 0; ks < 3; ++ks)
                acc1[nt] = __builtin_amdgcn_mfma_f32_16x16x32_bf16(
                    af[ks], bf[ks], acc1[nt], 0, 0, 0);
        }
        #pragma unroll
        for (int nt = 0; nt < 6; ++nt)
            #pragma unroll
            for (int j = 0; j < 4; ++j)
                sA[el_base + lg * 4 + j][nt * 16 + lr] =
                    f2bf(fmaxf(acc1[nt][j], 0.0f));
        asm volatile("s_waitcnt lgkmcnt(0)" ::: "memory");
        __builtin_amdgcn_sched_barrier(0);

        short8 a2[3];
        #pragma unroll
        for (int ks = 0; ks < 3; ++ks)
            a2[ks] = *(const short8*)&sA[el_base + lr][ks * 32 + lg * 8];
        f32x4 acc2[4];
        #pragma unroll
        for (int nt = 0; nt < 4; ++nt) {
            float bv = rb2[nt];
            acc2[nt] = f32x4{ bv, bv, bv, bv };
        }
        #pragma unroll
        for (int nt = 0; nt < 4; ++nt)
            #pragma unroll
            for (int ks = 0; ks < 3; ++ks)
                acc2[nt] = __builtin_amdgcn_mfma_f32_16x16x32_bf16(
                    a2[ks], bw2[nt][ks], acc2[nt], 0, 0, 0);

        int nd[4];
        #pragma unroll
        for (int j = 0; j < 4; ++j)
            nd[j] = ei[N_EDGES + e0 + el_base + lg * 4 + j];
        #pragma unroll
        for (int nt = 0; nt < 4; ++nt)
            #pragma unroll
            for (int j = 0; j < 4; ++j)
                atomicAdd(out + (size_t)nd[j] * OUT_DIM + nt * 16 + lr,
                          acc2[nt][j]);
    }
}

extern "C" void kernel_launch(void* const* d_in, const int* in_sizes, int n_in,
                              void* d_out, int out_size, void* d_ws, size_t ws_size,
                              hipStream_t stream) {
    const float* x  = (const float*)d_in[0];
    const int*   ei = (const int*)d_in[1];
    const float* ea = (const float*)d_in[2];
    const float* W1 = (const float*)d_in[3];
    const float* b1 = (const float*)d_in[4];
    const float* W2 = (const float*)d_in[5];
    const float* b2 = (const float*)d_in[6];
    float* out = (float*)d_out;

    // ws: eap[E*32]bf16 | xbf[N*64]bf16 | srcs[E] | dsts[E] | hist | starts | cursor | bsums
    char* ws = (char*)d_ws;
    const size_t eapOff  = 0;
    const size_t xbfOff  = eapOff + (size_t)N_EDGES * EDGE_DIM * 2;   // 51.2 MB
    const size_t srcsOff = xbfOff + (size_t)N_NODES * IN_DIM * 2;     // +6.4 MB
    const size_t dstsOff = srcsOff + (size_t)N_EDGES * 4;
    const size_t histOff = dstsOff + (size_t)N_EDGES * 4;
    const size_t strOff  = histOff + (size_t)N_NODES * 4;
    const size_t curOff  = strOff + (size_t)N_NODES * 4;
    const size_t bsumOff = curOff + (size_t)N_NODES * 4;
    const size_t need    = bsumOff + 64 * 4;

    if (ws_size >= need) {
        ushort* eap  = (ushort*)(ws + eapOff);
        ushort* xbf  = (ushort*)(ws + xbfOff);
        int* srcs    = (int*)(ws + srcsOff);
        int* dsts    = (int*)(ws + dstsOff);
        int* hist    = (int*)(ws + histOff);
        int* starts  = (int*)(ws + strOff);
        int* cursor  = (int*)(ws + curOff);
        int* bsums   = (int*)(ws + bsumOff);

        hipMemsetAsync(hist, 0, (size_t)N_NODES * 4, stream);
        hipMemsetAsync(out, 0, (size_t)N_NODES * OUT_DIM * 4, stream);
        hist_kernel<<<N_EDGES / 256, 256, 0, stream>>>(ei, hist);
        xbf_kernel<<<(N_NODES * 16 + 255) / 256, 256, 0, stream>>>(x, xbf);
        scan1_kernel<<<SCAN_NB, SCAN_B, 0, stream>>>(hist, starts, bsums);
        scan3_kernel<<<SCAN_NB, SCAN_B, 0, stream>>>(hist, starts, cursor, bsums);
        fill_permute_kernel<<<N_EDGES / 64, 256, 0, stream>>>(ei, ea, cursor, srcs, dsts, eap);
        edge_mlp_csr_kernel<<<GRID, THREADS, 0, stream>>>(
            xbf, eap, srcs, dsts, W1, b1, W2, b2, out);
        div_int_kernel<<<(N_NODES * OUT_DIM + 255) / 256, 256, 0, stream>>>(out, hist);
    } else {
        // fallback: atomic scatter path
        float* cnt = (float*)d_ws;  // N_NODES floats
        zero_kernel<<<(N_NODES * OUT_DIM + 255) / 256, 256, 0, stream>>>(out, cnt);
        edge_mlp_atomic_kernel<<<GRID, THREADS, 0, stream>>>(
            x, ei, ea, W1, b1, W2, b2, out, cnt);
        div_kernel<<<(N_NODES * OUT_DIM + 255) / 256, 256, 0, stream>>>(out, cnt);
    }
}